// Round 14
// baseline (162.561 us; speedup 1.0000x reference)
//
#include <hip/hip_runtime.h>

#define BN 65536
#define NT 512            // 8 waves/block
#define NBB 128           // batches per block (wave w owns batches w*16..w*16+15)
#define NBLK (BN / NBB)   // 512 blocks = 2 blocks/CU exactly, one pass

typedef unsigned int uint;
typedef unsigned short ushort;
typedef __attribute__((ext_vector_type(8))) short bf16x8;
typedef __attribute__((ext_vector_type(4))) float f32x4;

// LDS layout (u32 units): ping-pong A-frag buffers + masks + biases = 60224 B
#define L_A  0        // 6400 (1600 uint4)
#define L_B  6400     // 6400
#define L_MK 12800    // 1920: mask words [15][128]
#define L_B1 14720    // 112 f32
#define L_B2 14832    // 112
#define L_W3 14944    // 112
#define L_TOT 15056

// ws layout: u16 frag tables, then MK u32
// conv mats m*12800 (each=0,not=1,not2=2,empty=3); W1@51200 (7ti x 5ks); W2@69120 (7ti x 7ks)
#define WS_W1 51200
#define WS_W2 69120
#define WS_TOT 94208
#define WS_MK_BYTE 188416          // = WS_TOT*2, 16B aligned

__device__ __forceinline__ uint f2b(float f){           // bf16 rne bits
  uint u = __float_as_uint(f);
  return (u + 0x7FFFu + ((u >> 16) & 1u)) >> 16;
}
__device__ __forceinline__ float b2f(uint h){ return __uint_as_float(h << 16); }
__device__ __forceinline__ uint dupb(float f){ uint b = f2b(f); return b | (b << 16); }

union BU { uint u[4]; bf16x8 v; };

// ---------------- setup: build all MFMA A-fragment tables (hi/lo K-interleaved) ----------------
__global__ __launch_bounds__(256) void k_setup(
    const float* __restrict__ w_each, const float* __restrict__ w_not,
    const float* __restrict__ w_not2, const float* __restrict__ w_empty,
    const float* __restrict__ W1, const float* __restrict__ W2,
    ushort* __restrict__ wsp)
{
  int id = blockIdx.x * 256 + threadIdx.x;
  if (id >= WS_TOT) return;
  float val = 0.f;
  int part;
  if (id < 51200) {                       // conv mats
    int m = id / 12800, r = id % 12800;
    int fi = r >> 3, j = r & 7;
    int l = fi & 63, tk = fi >> 6;
    int ks = tk % 5, ti = tk / 5;
    int row = ti * 16 + (l & 15);         // output cell
    int k = ks * 32 + (l >> 4) * 8 + j;
    int t = k >> 1; part = k & 1;         // input cell, hi/lo slot
    if (row < 72 && t < 72) {
      int dr = t / 6 - row / 6 + 6, dc = t % 6 - row % 6 + 6;
      const float* w = m == 0 ? w_each : m == 1 ? w_not : m == 2 ? w_not2 : w_empty;
      if (dr >= 0 && dr < 13) val = w[dr * 13 + dc];
    }
  } else if (id < WS_W2) {                // W1
    int r = id - WS_W1;
    int fi = r >> 3, j = r & 7;
    int l = fi & 63, tk = fi >> 6;
    int ks = tk % 5, ti = tk / 5;
    int row = ti * 16 + (l & 15);
    int k = ks * 32 + (l >> 4) * 8 + j;
    int t = k >> 1; part = k & 1;
    if (row < 100 && t < 72) val = W1[row * 72 + t];
  } else {                                // W2
    int r = id - WS_W2;
    int fi = r >> 3, j = r & 7;
    int l = fi & 63, tk = fi >> 6;
    int ks = tk % 7, ti = tk / 7;
    int row = ti * 16 + (l & 15);
    int k = ks * 32 + (l >> 4) * 8 + j;
    int t = k >> 1; part = k & 1;
    if (row < 100 && t < 100) val = W2[row * 100 + t];
  }
  uint h = f2b(val);
  if (part) { float rem = val - b2f(h); h = f2b(rem); }
  wsp[id] = (ushort)h;
}

// ---------------- masks: per-batch kind bitmasks -> global [15][BN] ----------------
__global__ __launch_bounds__(256) void k_masks(const int* __restrict__ dots,
                                               uint* __restrict__ MKg)
{
  int b = blockIdx.x * 256 + threadIdx.x;
  uint mk[5][3] = {};
#pragma unroll
  for (int c = 0; c < 72; ++c) {
    int v = dots[c * BN + b];
#pragma unroll
    for (int k = 0; k < 5; ++k)
      mk[k][c >> 5] |= (uint)(v == k) << (c & 31);
  }
#pragma unroll
  for (int k = 0; k < 5; ++k)
#pragma unroll
    for (int w = 0; w < 3; ++w)
      MKg[(k * 3 + w) * BN + b] = mk[k][w];
}

// ---------------- async stage: frag table chunk -> LDS buffer via global_load_lds ----------------
template<int NTK, int KW, int KS0, int NKS>
__device__ __forceinline__ void gstage(uint* afb, const ushort* __restrict__ wsp,
                                       int baseU16, int wid, int lane)
{
  const uint4* src = (const uint4*)(wsp + baseU16);
  constexpr int NIT = (NTK * 64 + NT - 1) / NT;
#pragma unroll
  for (int it = 0; it < NIT; ++it) {
    int tk = it * (NT / 64) + wid;        // wave-uniform frag-group id (8 waves)
    if (tk < NTK) {
      int ksl = tk % NKS, ti = tk / NKS;  // compile-time NKS -> cheap
      const uint4* gp = src + (ti * KW + KS0 + ksl) * 64 + lane;   // per-lane global
      uint4* lp = (uint4*)afb + tk * 64;                            // wave-uniform LDS base
      __builtin_amdgcn_global_load_lds(
          (const __attribute__((address_space(1))) void*)gp,
          (__attribute__((address_space(3))) void*)lp, 16, 0, 0);
    }
  }
}

template<int NKS, int B0, int NBQ>
__device__ __forceinline__ void fcStep(const uint* sAF, const BU (&Bq)[NBQ],
                                       f32x4 (&Acc)[7], int lane)
{
  const bf16x8* AF = (const bf16x8*)sAF;
#pragma unroll
  for (int ti = 0; ti < 7; ++ti)
#pragma unroll
    for (int ksl = 0; ksl < NKS; ++ksl)
      Acc[ti] = __builtin_amdgcn_mfma_f32_16x16x32_bf16(
          AF[(ti * NKS + ksl) * 64 + lane], Bq[B0 + ksl].v, Acc[ti], 0, 0, 0);
}

// r13 lesson: __launch_bounds__(512,4) capped VGPR at 64 -> 600 MB spill.
// Use plain launch_bounds + waves_per_eu(4,4): VGPR cap 128 >= ~108 live,
// LDS (60.4 KB) caps at 2 blocks/CU -> 16 waves/CU = 4 waves/EU.
__global__ __launch_bounds__(NT)
__attribute__((amdgpu_waves_per_eu(4, 4)))
void k_main(
    const uint* __restrict__ MKg, const ushort* __restrict__ wsp,
    const float* __restrict__ b_each, const float* __restrict__ b_not,
    const float* __restrict__ b_not2, const float* __restrict__ b_empty,
    const float* __restrict__ b1, const float* __restrict__ b2,
    const float* __restrict__ W3, const float* __restrict__ b3,
    float* __restrict__ out)
{
  __shared__ uint sB[L_TOT];
  const int tid = threadIdx.x;
  const int wid = tid >> 6, lane = tid & 63;
  const int grp = lane >> 4;
  const int bl = wid * 16 + (lane & 15);  // local batch of this lane's B/D columns (0..127)
  const int gq = grp * 4;

  const float c_each = *b_each, c_not = *b_not, c_not2 = *b_not2, c_empty = *b_empty;
  const float c_b3 = *b3;

  // ---- prologue: biases + masks to LDS, stage empty table into buffer A ----
  if (tid < 112) {
    ((float*)(sB + L_B1))[tid] = (tid < 100) ? b1[tid] : 0.f;
    ((float*)(sB + L_B2))[tid] = (tid < 100) ? b2[tid] : 0.f;
    ((float*)(sB + L_W3))[tid] = (tid < 100) ? W3[tid] : 0.f;
  }
#pragma unroll
  for (int it = 0; it < 4; ++it) {        // 1920 mask words [15][128]
    int i = it * NT + tid;
    if (i < 1920) {
      int w = i >> 7, b = i & 127;
      sB[L_MK + i] = MKg[w * BN + blockIdx.x * NBB + b];
    }
  }
  gstage<25, 5, 0, 5>(sB + L_A, wsp, 3 * 12800, wid, lane);   // empty -> A
  __syncthreads();

  uint mkr[15];
#pragma unroll
  for (int w = 0; w < 15; ++w) mkr[w] = sB[L_MK + w * 128 + bl];

  f32x4 S5[5], A5[5];
  uint zws[5] = {0, 0, 0, 0, 0};

  // ================ empty conv -> S, plus z bytes ================
  gstage<25, 5, 0, 5>(sB + L_B, wsp, 0, wid, lane);           // each -> B
  {
    const bf16x8* AF = (const bf16x8*)(sB + L_A);
    BU Bv[5];
#pragma unroll
    for (int ks = 0; ks < 5; ++ks) {
      uint wv = mkr[0 * 3 + (ks >> 1)];
      int base = ((ks * 16) & 31) + gq;
#pragma unroll
      for (int q = 0; q < 4; ++q)
        Bv[ks].u[q] = ((wv >> (base + q)) & 1u) ? 0x3F803F80u : 0u;
    }
#pragma unroll
    for (int ti = 0; ti < 5; ++ti) {
      f32x4 d = {c_empty, c_empty, c_empty, c_empty};
#pragma unroll
      for (int ks = 0; ks < 5; ++ks)
        d = __builtin_amdgcn_mfma_f32_16x16x32_bf16(AF[(ti * 5 + ks) * 64 + lane], Bv[ks].v, d, 0, 0, 0);
      S5[ti] = d;
    }
  }
#pragma unroll
  for (int k = 1; k <= 4; ++k) {
#pragma unroll
    for (int ti = 0; ti < 5; ++ti) {
      uint wv = mkr[k * 3 + (ti >> 1)];
      int base = ((ti * 16) & 31) + gq;
#pragma unroll
      for (int r = 0; r < 4; ++r) {
        float mb = (float)((wv >> (base + r)) & 1u);
        if (S5[ti][r] + mb > 0.f) zws[ti] |= 1u << (r * 8 + (k - 1));
      }
    }
  }
  __syncthreads();                        // each-table staged; empty reads done

  // ================ each convs: S += ecv_k at kind-k cells ================
  gstage<25, 5, 0, 5>(sB + L_A, wsp, 1 * 12800, wid, lane);   // not -> A
  {
    const bf16x8* AF = (const bf16x8*)(sB + L_B);
#pragma unroll 1
    for (int k = 1; k <= 4; ++k) {        // unroll 1: keep VGPR pressure low (r9 spill lesson)
      BU Bv[5];
#pragma unroll
      for (int ks = 0; ks < 5; ++ks) {
        uint wv = mkr[k * 3 + (ks >> 1)];
        int base = ((ks * 16) & 31) + gq;
#pragma unroll
        for (int q = 0; q < 4; ++q)
          Bv[ks].u[q] = ((wv >> (base + q)) & 1u) ? 0x3F803F80u : 0u;
      }
#pragma unroll
      for (int ti = 0; ti < 5; ++ti) {
        f32x4 d = {c_each, c_each, c_each, c_each};
#pragma unroll
        for (int ks = 0; ks < 5; ++ks)
          d = __builtin_amdgcn_mfma_f32_16x16x32_bf16(AF[(ti * 5 + ks) * 64 + lane], Bv[ks].v, d, 0, 0, 0);
        uint wv = mkr[k * 3 + (ti >> 1)];
        int base = ((ti * 16) & 31) + gq;
#pragma unroll
        for (int r = 0; r < 4; ++r)
          if ((wv >> (base + r)) & 1u) S5[ti][r] += d[r];
      }
    }
  }
  // S is CLEAN (empty + ecv_sel); acv init: 0 at empty cells
#pragma unroll
  for (int ti = 0; ti < 5; ++ti) {
    uint wv = mkr[0 * 3 + (ti >> 1)];
    int base = ((ti * 16) & 31) + gq;
#pragma unroll
    for (int r = 0; r < 4; ++r)
      A5[ti][r] = ((wv >> (base + r)) & 1u) ? 0.f : S5[ti][r];
  }
  __syncthreads();                        // not-table staged; each reads done

  // ================ not convs: acv -= not_conv at kind cells (input ~z) ================
  gstage<25, 5, 0, 5>(sB + L_B, wsp, 2 * 12800, wid, lane);   // not2 -> B
  {
    const bf16x8* AF = (const bf16x8*)(sB + L_A);
#pragma unroll 1
    for (int k = 1; k <= 4; ++k) {
      BU Bv[5];
#pragma unroll
      for (int ks = 0; ks < 5; ++ks) {
#pragma unroll
        for (int q = 0; q < 4; ++q)
          Bv[ks].u[q] = ((zws[ks] >> (q * 8 + (k - 1))) & 1u) ? 0u : 0x3F803F80u;
      }
#pragma unroll
      for (int ti = 0; ti < 5; ++ti) {
        f32x4 d = {c_not, c_not, c_not, c_not};
#pragma unroll
        for (int ks = 0; ks < 5; ++ks)
          d = __builtin_amdgcn_mfma_f32_16x16x32_bf16(AF[(ti * 5 + ks) * 64 + lane], Bv[ks].v, d, 0, 0, 0);
        uint wv = mkr[k * 3 + (ti >> 1)];
        int base = ((ti * 16) & 31) + gq;
#pragma unroll
        for (int r = 0; r < 4; ++r)
          if ((wv >> (base + r)) & 1u) A5[ti][r] -= d[r];
      }
    }
  }
  __syncthreads();                        // not2-table staged; not reads done

  // ================ not2 convs (phase C): 4 sequential, register state ================
  gstage<21, 5, 0, 3>(sB + L_A, wsp, WS_W1, wid, lane);       // FC1 chunk a -> A
  {
    const bf16x8* AF = (const bf16x8*)(sB + L_B);
#pragma unroll 1
    for (int k = 1; k <= 4; ++k) {
      BU Bv[5];
#pragma unroll
      for (int ks = 0; ks < 5; ++ks) {
#pragma unroll
        for (int q = 0; q < 4; ++q)
          Bv[ks].u[q] = ((zws[ks] >> (q * 8 + (k - 1))) & 1u) ? 0u : dupb(A5[ks][q]);
      }
#pragma unroll
      for (int ti = 0; ti < 5; ++ti) {
        f32x4 d = {c_not2, c_not2, c_not2, c_not2};
#pragma unroll
        for (int ks = 0; ks < 5; ++ks)
          d = __builtin_amdgcn_mfma_f32_16x16x32_bf16(AF[(ti * 5 + ks) * 64 + lane], Bv[ks].v, d, 0, 0, 0);
        uint wv = mkr[k * 3 + (ti >> 1)];
        int base = ((ti * 16) & 31) + gq;
#pragma unroll
        for (int r = 0; r < 4; ++r)
          if ((wv >> (base + r)) & 1u) A5[ti][r] += S5[ti][r] + d[r];
      }
    }
  }
  __syncthreads();                        // FC1a staged; not2 reads done

  // ================ FC1: h = leaky(W1 x + b1) ================
  BU Bx[5];
#pragma unroll
  for (int ks = 0; ks < 5; ++ks)
#pragma unroll
    for (int q = 0; q < 4; ++q) Bx[ks].u[q] = dupb(A5[ks][q]);
  f32x4 H[7];
#pragma unroll
  for (int ti = 0; ti < 7; ++ti) H[ti] = ((const f32x4*)(sB + L_B1))[ti * 4 + grp];

  gstage<14, 5, 3, 2>(sB + L_B, wsp, WS_W1, wid, lane);       // FC1 chunk b -> B
  fcStep<3, 0>(sB + L_A, Bx, H, lane);
  __syncthreads();
  gstage<21, 7, 0, 3>(sB + L_A, wsp, WS_W2, wid, lane);       // FC2 chunk a -> A
  fcStep<2, 3>(sB + L_B, Bx, H, lane);

  BU By[7];
#pragma unroll
  for (int ti = 0; ti < 7; ++ti) {
#pragma unroll
    for (int r = 0; r < 4; ++r) { float x = H[ti][r]; H[ti][r] = fmaxf(x, 0.2f * x); }
#pragma unroll
    for (int r = 0; r < 4; ++r) By[ti].u[r] = dupb(H[ti][r]);
  }
  f32x4 G[7];
#pragma unroll
  for (int ti = 0; ti < 7; ++ti) G[ti] = ((const f32x4*)(sB + L_B2))[ti * 4 + grp];
  __syncthreads();

  // ================ FC2: g = leaky(W2 h + b2) ================
  gstage<14, 7, 3, 2>(sB + L_B, wsp, WS_W2, wid, lane);       // FC2 chunk b -> B
  fcStep<3, 0>(sB + L_A, By, G, lane);
  __syncthreads();
  gstage<14, 7, 5, 2>(sB + L_A, wsp, WS_W2, wid, lane);       // FC2 chunk c -> A
  fcStep<2, 3>(sB + L_B, By, G, lane);
  __syncthreads();
  fcStep<2, 5>(sB + L_A, By, G, lane);

  // ================ FC3: out = W3 . leaky(g) + b3 ================
  float pd = 0.f;
#pragma unroll
  for (int ti = 0; ti < 7; ++ti) {
    f32x4 w3v = ((const f32x4*)(sB + L_W3))[ti * 4 + grp];
#pragma unroll
    for (int r = 0; r < 4; ++r) {
      float g = G[ti][r];
      g = fmaxf(g, 0.2f * g);
      pd = fmaf(w3v[r], g, pd);
    }
  }
  pd += __shfl_xor(pd, 16);
  pd += __shfl_xor(pd, 32);
  if (lane < 16) out[blockIdx.x * NBB + wid * 16 + lane] = pd + c_b3;
}

extern "C" void kernel_launch(void* const* d_in, const int* in_sizes, int n_in,
                              void* d_out, int out_size, void* d_ws, size_t ws_size,
                              hipStream_t stream)
{
  const int*   dots    = (const int*)d_in[0];
  const float* w_each  = (const float*)d_in[1];
  const float* b_each  = (const float*)d_in[2];
  const float* w_not   = (const float*)d_in[3];
  const float* b_not   = (const float*)d_in[4];
  const float* w_not2  = (const float*)d_in[5];
  const float* b_not2  = (const float*)d_in[6];
  const float* w_empty = (const float*)d_in[7];
  const float* b_empty = (const float*)d_in[8];
  const float* W1 = (const float*)d_in[9];
  const float* b1 = (const float*)d_in[10];
  const float* W2 = (const float*)d_in[11];
  const float* b2 = (const float*)d_in[12];
  const float* W3 = (const float*)d_in[13];
  const float* b3 = (const float*)d_in[14];

  (void)in_sizes; (void)n_in; (void)out_size; (void)ws_size;

  ushort* wsp = (ushort*)d_ws;
  uint*   MKg = (uint*)((char*)d_ws + WS_MK_BYTE);

  k_setup<<<(WS_TOT + 255) / 256, 256, 0, stream>>>(
      w_each, w_not, w_not2, w_empty, W1, W2, wsp);
  k_masks<<<BN / 256, 256, 0, stream>>>(dots, MKg);
  k_main<<<NBLK, NT, 0, stream>>>(
      MKg, wsp, b_each, b_not, b_not2, b_empty, b1, b2, W3, b3, (float*)d_out);
}

// Round 15
// 58.221 us; speedup vs baseline: 2.7922x; 2.7922x over previous
//
#include <hip/hip_runtime.h>

#define BN 65536
#define NT 256
#define NBB 64            // batches per block (wave w owns batches w*16..w*16+15)
#define NBLK (BN / NBB)   // 1024 blocks

typedef unsigned int uint;
typedef unsigned short ushort;
typedef __attribute__((ext_vector_type(8))) short bf16x8;
typedef __attribute__((ext_vector_type(4))) float f32x4;

// LDS layout (u32 units): ping-pong A-frag buffers + biases = 52544 B  (<53.3 KB -> 3 blocks/CU)
#define L_A  0        // 6400 (1600 uint4)
#define L_B  6400     // 6400
#define L_B1 12800    // 112 f32
#define L_B2 12912    // 112
#define L_W3 13024    // 112
#define L_TOT 13136

// ws layout: u16 frag tables, then MK u32
// conv mats m*12800 (each=0,not=1,not2=2,empty=3); W1@51200 (7ti x 5ks); W2@69120 (7ti x 7ks)
#define WS_W1 51200
#define WS_W2 69120
#define WS_TOT 94208
#define WS_MK_BYTE 188416          // = WS_TOT*2, 16B aligned

__device__ __forceinline__ uint f2b(float f){           // bf16 rne bits
  uint u = __float_as_uint(f);
  return (u + 0x7FFFu + ((u >> 16) & 1u)) >> 16;
}
__device__ __forceinline__ float b2f(uint h){ return __uint_as_float(h << 16); }
__device__ __forceinline__ uint dupb(float f){ uint b = f2b(f); return b | (b << 16); }

union BU { uint u[4]; bf16x8 v; };

// ---------------- setup: build all MFMA A-fragment tables (hi/lo K-interleaved) ----------------
__global__ __launch_bounds__(256) void k_setup(
    const float* __restrict__ w_each, const float* __restrict__ w_not,
    const float* __restrict__ w_not2, const float* __restrict__ w_empty,
    const float* __restrict__ W1, const float* __restrict__ W2,
    ushort* __restrict__ wsp)
{
  int id = blockIdx.x * 256 + threadIdx.x;
  if (id >= WS_TOT) return;
  float val = 0.f;
  int part;
  if (id < 51200) {                       // conv mats
    int m = id / 12800, r = id % 12800;
    int fi = r >> 3, j = r & 7;
    int l = fi & 63, tk = fi >> 6;
    int ks = tk % 5, ti = tk / 5;
    int row = ti * 16 + (l & 15);         // output cell
    int k = ks * 32 + (l >> 4) * 8 + j;
    int t = k >> 1; part = k & 1;         // input cell, hi/lo slot
    if (row < 72 && t < 72) {
      int dr = t / 6 - row / 6 + 6, dc = t % 6 - row % 6 + 6;
      const float* w = m == 0 ? w_each : m == 1 ? w_not : m == 2 ? w_not2 : w_empty;
      if (dr >= 0 && dr < 13) val = w[dr * 13 + dc];
    }
  } else if (id < WS_W2) {                // W1
    int r = id - WS_W1;
    int fi = r >> 3, j = r & 7;
    int l = fi & 63, tk = fi >> 6;
    int ks = tk % 5, ti = tk / 5;
    int row = ti * 16 + (l & 15);
    int k = ks * 32 + (l >> 4) * 8 + j;
    int t = k >> 1; part = k & 1;
    if (row < 100 && t < 72) val = W1[row * 72 + t];
  } else {                                // W2
    int r = id - WS_W2;
    int fi = r >> 3, j = r & 7;
    int l = fi & 63, tk = fi >> 6;
    int ks = tk % 7, ti = tk / 7;
    int row = ti * 16 + (l & 15);
    int k = ks * 32 + (l >> 4) * 8 + j;
    int t = k >> 1; part = k & 1;
    if (row < 100 && t < 100) val = W2[row * 100 + t];
  }
  uint h = f2b(val);
  if (part) { float rem = val - b2f(h); h = f2b(rem); }
  wsp[id] = (ushort)h;
}

// ---------------- masks: per-batch kind bitmasks -> global [15][BN] ----------------
__global__ __launch_bounds__(256) void k_masks(const int* __restrict__ dots,
                                               uint* __restrict__ MKg)
{
  int b = blockIdx.x * 256 + threadIdx.x;
  uint mk[5][3] = {};
#pragma unroll
  for (int c = 0; c < 72; ++c) {
    int v = dots[c * BN + b];
#pragma unroll
    for (int k = 0; k < 5; ++k)
      mk[k][c >> 5] |= (uint)(v == k) << (c & 31);
  }
#pragma unroll
  for (int k = 0; k < 5; ++k)
#pragma unroll
    for (int w = 0; w < 3; ++w)
      MKg[(k * 3 + w) * BN + b] = mk[k][w];
}

// ---------------- async stage: frag table chunk -> LDS buffer via global_load_lds ----------------
template<int NTK, int KW, int KS0, int NKS>
__device__ __forceinline__ void gstage(uint* afb, const ushort* __restrict__ wsp,
                                       int baseU16, int wid, int lane)
{
  const uint4* src = (const uint4*)(wsp + baseU16);
  constexpr int NIT = (NTK * 64 + NT - 1) / NT;
#pragma unroll
  for (int it = 0; it < NIT; ++it) {
    int tk = it * 4 + wid;                // wave-uniform frag-group id
    if (tk < NTK) {
      int ksl = tk % NKS, ti = tk / NKS;  // compile-time NKS -> cheap
      const uint4* gp = src + (ti * KW + KS0 + ksl) * 64 + lane;   // per-lane global
      uint4* lp = (uint4*)afb + tk * 64;                            // wave-uniform LDS base
      __builtin_amdgcn_global_load_lds(
          (const __attribute__((address_space(1))) void*)gp,
          (__attribute__((address_space(3))) void*)lp, 16, 0, 0);
    }
  }
}

template<int NKS, int B0, int NBQ>
__device__ __forceinline__ void fcStep(const uint* sAF, const BU (&Bq)[NBQ],
                                       f32x4 (&Acc)[7], int lane)
{
  const bf16x8* AF = (const bf16x8*)sAF;
#pragma unroll
  for (int ti = 0; ti < 7; ++ti)
#pragma unroll
    for (int ksl = 0; ksl < NKS; ++ksl)
      Acc[ti] = __builtin_amdgcn_mfma_f32_16x16x32_bf16(
          AF[(ti * NKS + ksl) * 64 + lane], Bq[B0 + ksl].v, Acc[ti], 0, 0, 0);
}

// r13/r14 lesson: any 4-waves/EU attribute -> VGPR cap 64 -> catastrophic spill.
// Keep the known-good (256,2) allocator config (VGPR ~108, no spill) and win
// occupancy via LDS: 52.5 KB -> 3 blocks/CU = 12 waves/CU at runtime.
__global__ __launch_bounds__(NT, 2) void k_main(
    const uint* __restrict__ MKg, const ushort* __restrict__ wsp,
    const float* __restrict__ b_each, const float* __restrict__ b_not,
    const float* __restrict__ b_not2, const float* __restrict__ b_empty,
    const float* __restrict__ b1, const float* __restrict__ b2,
    const float* __restrict__ W3, const float* __restrict__ b3,
    float* __restrict__ out)
{
  __shared__ uint sB[L_TOT];
  const int tid = threadIdx.x;
  const int wid = tid >> 6, lane = tid & 63;
  const int grp = lane >> 4;
  const int bl = wid * 16 + (lane & 15);  // local batch of this lane's B/D columns
  const int gq = grp * 4;

  const float c_each = *b_each, c_not = *b_not, c_not2 = *b_not2, c_empty = *b_empty;
  const float c_b3 = *b3;

  // ---- prologue: biases to LDS, masks straight to registers, stage empty table ----
  if (tid < 112) {
    ((float*)(sB + L_B1))[tid] = (tid < 100) ? b1[tid] : 0.f;
    ((float*)(sB + L_B2))[tid] = (tid < 100) ? b2[tid] : 0.f;
    ((float*)(sB + L_W3))[tid] = (tid < 100) ? W3[tid] : 0.f;
  }
  gstage<25, 5, 0, 5>(sB + L_A, wsp, 3 * 12800, wid, lane);   // empty -> A

  uint mkr[15];
  {
    const int gb = blockIdx.x * NBB + bl;
#pragma unroll
    for (int w = 0; w < 15; ++w) mkr[w] = MKg[w * BN + gb];   // L2-resident, 64B segments
  }
  __syncthreads();

  f32x4 S5[5], A5[5];
  uint zws[5] = {0, 0, 0, 0, 0};

  // ================ empty conv -> S, plus z bytes ================
  gstage<25, 5, 0, 5>(sB + L_B, wsp, 0, wid, lane);           // each -> B
  {
    const bf16x8* AF = (const bf16x8*)(sB + L_A);
    BU Bv[5];
#pragma unroll
    for (int ks = 0; ks < 5; ++ks) {
      uint wv = mkr[0 * 3 + (ks >> 1)];
      int base = ((ks * 16) & 31) + gq;
#pragma unroll
      for (int q = 0; q < 4; ++q)
        Bv[ks].u[q] = ((wv >> (base + q)) & 1u) ? 0x3F803F80u : 0u;
    }
#pragma unroll
    for (int ti = 0; ti < 5; ++ti) {
      f32x4 d = {c_empty, c_empty, c_empty, c_empty};
#pragma unroll
      for (int ks = 0; ks < 5; ++ks)
        d = __builtin_amdgcn_mfma_f32_16x16x32_bf16(AF[(ti * 5 + ks) * 64 + lane], Bv[ks].v, d, 0, 0, 0);
      S5[ti] = d;
    }
  }
#pragma unroll
  for (int k = 1; k <= 4; ++k) {
#pragma unroll
    for (int ti = 0; ti < 5; ++ti) {
      uint wv = mkr[k * 3 + (ti >> 1)];
      int base = ((ti * 16) & 31) + gq;
#pragma unroll
      for (int r = 0; r < 4; ++r) {
        float mb = (float)((wv >> (base + r)) & 1u);
        if (S5[ti][r] + mb > 0.f) zws[ti] |= 1u << (r * 8 + (k - 1));
      }
    }
  }
  __syncthreads();                        // each-table staged; empty reads done

  // ================ each convs: S += ecv_k at kind-k cells ================
  gstage<25, 5, 0, 5>(sB + L_A, wsp, 1 * 12800, wid, lane);   // not -> A
  {
    const bf16x8* AF = (const bf16x8*)(sB + L_B);
#pragma unroll 1
    for (int k = 1; k <= 4; ++k) {        // unroll 1: keep VGPR pressure low (r9 spill lesson)
      BU Bv[5];
#pragma unroll
      for (int ks = 0; ks < 5; ++ks) {
        uint wv = mkr[k * 3 + (ks >> 1)];
        int base = ((ks * 16) & 31) + gq;
#pragma unroll
        for (int q = 0; q < 4; ++q)
          Bv[ks].u[q] = ((wv >> (base + q)) & 1u) ? 0x3F803F80u : 0u;
      }
#pragma unroll
      for (int ti = 0; ti < 5; ++ti) {
        f32x4 d = {c_each, c_each, c_each, c_each};
#pragma unroll
        for (int ks = 0; ks < 5; ++ks)
          d = __builtin_amdgcn_mfma_f32_16x16x32_bf16(AF[(ti * 5 + ks) * 64 + lane], Bv[ks].v, d, 0, 0, 0);
        uint wv = mkr[k * 3 + (ti >> 1)];
        int base = ((ti * 16) & 31) + gq;
#pragma unroll
        for (int r = 0; r < 4; ++r)
          if ((wv >> (base + r)) & 1u) S5[ti][r] += d[r];
      }
    }
  }
  // S is CLEAN (empty + ecv_sel); acv init: 0 at empty cells
#pragma unroll
  for (int ti = 0; ti < 5; ++ti) {
    uint wv = mkr[0 * 3 + (ti >> 1)];
    int base = ((ti * 16) & 31) + gq;
#pragma unroll
    for (int r = 0; r < 4; ++r)
      A5[ti][r] = ((wv >> (base + r)) & 1u) ? 0.f : S5[ti][r];
  }
  __syncthreads();                        // not-table staged; each reads done

  // ================ not convs: acv -= not_conv at kind cells (input ~z) ================
  gstage<25, 5, 0, 5>(sB + L_B, wsp, 2 * 12800, wid, lane);   // not2 -> B
  {
    const bf16x8* AF = (const bf16x8*)(sB + L_A);
#pragma unroll 1
    for (int k = 1; k <= 4; ++k) {
      BU Bv[5];
#pragma unroll
      for (int ks = 0; ks < 5; ++ks) {
#pragma unroll
        for (int q = 0; q < 4; ++q)
          Bv[ks].u[q] = ((zws[ks] >> (q * 8 + (k - 1))) & 1u) ? 0u : 0x3F803F80u;
      }
#pragma unroll
      for (int ti = 0; ti < 5; ++ti) {
        f32x4 d = {c_not, c_not, c_not, c_not};
#pragma unroll
        for (int ks = 0; ks < 5; ++ks)
          d = __builtin_amdgcn_mfma_f32_16x16x32_bf16(AF[(ti * 5 + ks) * 64 + lane], Bv[ks].v, d, 0, 0, 0);
        uint wv = mkr[k * 3 + (ti >> 1)];
        int base = ((ti * 16) & 31) + gq;
#pragma unroll
        for (int r = 0; r < 4; ++r)
          if ((wv >> (base + r)) & 1u) A5[ti][r] -= d[r];
      }
    }
  }
  __syncthreads();                        // not2-table staged; not reads done

  // ================ not2 convs (phase C): 4 sequential, register state ================
  gstage<21, 5, 0, 3>(sB + L_A, wsp, WS_W1, wid, lane);       // FC1 chunk a -> A
  {
    const bf16x8* AF = (const bf16x8*)(sB + L_B);
#pragma unroll 1
    for (int k = 1; k <= 4; ++k) {
      BU Bv[5];
#pragma unroll
      for (int ks = 0; ks < 5; ++ks) {
#pragma unroll
        for (int q = 0; q < 4; ++q)
          Bv[ks].u[q] = ((zws[ks] >> (q * 8 + (k - 1))) & 1u) ? 0u : dupb(A5[ks][q]);
      }
#pragma unroll
      for (int ti = 0; ti < 5; ++ti) {
        f32x4 d = {c_not2, c_not2, c_not2, c_not2};
#pragma unroll
        for (int ks = 0; ks < 5; ++ks)
          d = __builtin_amdgcn_mfma_f32_16x16x32_bf16(AF[(ti * 5 + ks) * 64 + lane], Bv[ks].v, d, 0, 0, 0);
        uint wv = mkr[k * 3 + (ti >> 1)];
        int base = ((ti * 16) & 31) + gq;
#pragma unroll
        for (int r = 0; r < 4; ++r)
          if ((wv >> (base + r)) & 1u) A5[ti][r] += S5[ti][r] + d[r];
      }
    }
  }
  __syncthreads();                        // FC1a staged; not2 reads done

  // ================ FC1: h = leaky(W1 x + b1) ================
  BU Bx[5];
#pragma unroll
  for (int ks = 0; ks < 5; ++ks)
#pragma unroll
    for (int q = 0; q < 4; ++q) Bx[ks].u[q] = dupb(A5[ks][q]);
  f32x4 H[7];
#pragma unroll
  for (int ti = 0; ti < 7; ++ti) H[ti] = ((const f32x4*)(sB + L_B1))[ti * 4 + grp];

  gstage<14, 5, 3, 2>(sB + L_B, wsp, WS_W1, wid, lane);       // FC1 chunk b -> B
  fcStep<3, 0>(sB + L_A, Bx, H, lane);
  __syncthreads();
  gstage<21, 7, 0, 3>(sB + L_A, wsp, WS_W2, wid, lane);       // FC2 chunk a -> A
  fcStep<2, 3>(sB + L_B, Bx, H, lane);

  BU By[7];
#pragma unroll
  for (int ti = 0; ti < 7; ++ti) {
#pragma unroll
    for (int r = 0; r < 4; ++r) { float x = H[ti][r]; H[ti][r] = fmaxf(x, 0.2f * x); }
#pragma unroll
    for (int r = 0; r < 4; ++r) By[ti].u[r] = dupb(H[ti][r]);
  }
  f32x4 G[7];
#pragma unroll
  for (int ti = 0; ti < 7; ++ti) G[ti] = ((const f32x4*)(sB + L_B2))[ti * 4 + grp];
  __syncthreads();

  // ================ FC2: g = leaky(W2 h + b2) ================
  gstage<14, 7, 3, 2>(sB + L_B, wsp, WS_W2, wid, lane);       // FC2 chunk b -> B
  fcStep<3, 0>(sB + L_A, By, G, lane);
  __syncthreads();
  gstage<14, 7, 5, 2>(sB + L_A, wsp, WS_W2, wid, lane);       // FC2 chunk c -> A
  fcStep<2, 3>(sB + L_B, By, G, lane);
  __syncthreads();
  fcStep<2, 5>(sB + L_A, By, G, lane);

  // ================ FC3: out = W3 . leaky(g) + b3 ================
  float pd = 0.f;
#pragma unroll
  for (int ti = 0; ti < 7; ++ti) {
    f32x4 w3v = ((const f32x4*)(sB + L_W3))[ti * 4 + grp];
#pragma unroll
    for (int r = 0; r < 4; ++r) {
      float g = G[ti][r];
      g = fmaxf(g, 0.2f * g);
      pd = fmaf(w3v[r], g, pd);
    }
  }
  pd += __shfl_xor(pd, 16);
  pd += __shfl_xor(pd, 32);
  if (lane < 16) out[blockIdx.x * NBB + wid * 16 + lane] = pd + c_b3;
}

extern "C" void kernel_launch(void* const* d_in, const int* in_sizes, int n_in,
                              void* d_out, int out_size, void* d_ws, size_t ws_size,
                              hipStream_t stream)
{
  const int*   dots    = (const int*)d_in[0];
  const float* w_each  = (const float*)d_in[1];
  const float* b_each  = (const float*)d_in[2];
  const float* w_not   = (const float*)d_in[3];
  const float* b_not   = (const float*)d_in[4];
  const float* w_not2  = (const float*)d_in[5];
  const float* b_not2  = (const float*)d_in[6];
  const float* w_empty = (const float*)d_in[7];
  const float* b_empty = (const float*)d_in[8];
  const float* W1 = (const float*)d_in[9];
  const float* b1 = (const float*)d_in[10];
  const float* W2 = (const float*)d_in[11];
  const float* b2 = (const float*)d_in[12];
  const float* W3 = (const float*)d_in[13];
  const float* b3 = (const float*)d_in[14];

  (void)in_sizes; (void)n_in; (void)out_size; (void)ws_size;

  ushort* wsp = (ushort*)d_ws;
  uint*   MKg = (uint*)((char*)d_ws + WS_MK_BYTE);

  k_setup<<<(WS_TOT + 255) / 256, 256, 0, stream>>>(
      w_each, w_not, w_not2, w_empty, W1, W2, wsp);
  k_masks<<<BN / 256, 256, 0, stream>>>(dots, MKg);
  k_main<<<NBLK, NT, 0, stream>>>(
      MKg, wsp, b_each, b_not, b_not2, b_empty, b1, b2, W3, b3, (float*)d_out);
}

// Round 16
// 53.974 us; speedup vs baseline: 3.0118x; 1.0787x over previous
//
#include <hip/hip_runtime.h>

#define BN 65536
#define NT 256
#define NBB 64            // batches per block (wave w owns batches w*16..w*16+15)
#define NBLK (BN / NBB)   // 1024 blocks

typedef unsigned int uint;
typedef unsigned short ushort;
typedef __attribute__((ext_vector_type(8))) short bf16x8;
typedef __attribute__((ext_vector_type(4))) float f32x4;

// LDS layout (u32 units): ping-pong A-frag buffers + biases = 52544 B  (<53.3 KB -> 3 blocks/CU)
#define L_A  0        // 6400 (1600 uint4)
#define L_B  6400     // 6400
#define L_B1 12800    // 112 f32
#define L_B2 12912    // 112
#define L_W3 13024    // 112
#define L_TOT 13136

// ws layout: u16 frag tables, then MK u32
// conv mats m*12800 (each=0,not=1,not2=2,empty=3); W1@51200 (7ti x 5ks); W2@69120 (7ti x 7ks)
#define WS_W1 51200
#define WS_W2 69120
#define WS_TOT 94208
#define WS_MK_BYTE 188416          // = WS_TOT*2, 16B aligned
#define SETUP_BLOCKS 368           // ceil(WS_TOT/256)

// statically-zero conv fragment blocks: |board-row gap| > 6 -> outside 13x13 kernel
#define ZBLK(ti, ks) (((ti) == 0 && (ks) == 4) || ((ti) == 4 && (ks) == 0))

__device__ __forceinline__ uint f2b(float f){           // bf16 rne bits
  uint u = __float_as_uint(f);
  return (u + 0x7FFFu + ((u >> 16) & 1u)) >> 16;
}
__device__ __forceinline__ float b2f(uint h){ return __uint_as_float(h << 16); }
__device__ __forceinline__ uint dup_cvt(float f){       // packed bf16 dup via HW cvt (RNE)
  uint r;
  asm("v_cvt_pk_bf16_f32 %0, %1, %2" : "=v"(r) : "v"(f), "v"(f));
  return r;
}

union BU { uint u[4]; bf16x8 v; };

// ---------------- prep: frag tables + per-batch kind bitmasks (fused) ----------------
__global__ __launch_bounds__(256) void k_prep(
    const float* __restrict__ w_each, const float* __restrict__ w_not,
    const float* __restrict__ w_not2, const float* __restrict__ w_empty,
    const float* __restrict__ W1, const float* __restrict__ W2,
    const int* __restrict__ dots,
    ushort* __restrict__ wsp, uint* __restrict__ MKg)
{
  if (blockIdx.x >= SETUP_BLOCKS) {       // mask-building blocks
    int b = (blockIdx.x - SETUP_BLOCKS) * 256 + threadIdx.x;
    uint mk[5][3] = {};
#pragma unroll
    for (int c = 0; c < 72; ++c) {
      int v = dots[c * BN + b];
#pragma unroll
      for (int k = 0; k < 5; ++k)
        mk[k][c >> 5] |= (uint)(v == k) << (c & 31);
    }
#pragma unroll
    for (int k = 0; k < 5; ++k)
#pragma unroll
      for (int w = 0; w < 3; ++w)
        MKg[(k * 3 + w) * BN + b] = mk[k][w];
    return;
  }
  int id = blockIdx.x * 256 + threadIdx.x;
  if (id >= WS_TOT) return;
  float val = 0.f;
  int part;
  if (id < 51200) {                       // conv mats
    int m = id / 12800, r = id % 12800;
    int fi = r >> 3, j = r & 7;
    int l = fi & 63, tk = fi >> 6;
    int ks = tk % 5, ti = tk / 5;
    int row = ti * 16 + (l & 15);         // output cell
    int k = ks * 32 + (l >> 4) * 8 + j;
    int t = k >> 1; part = k & 1;         // input cell, hi/lo slot
    if (row < 72 && t < 72) {
      int dr = t / 6 - row / 6 + 6, dc = t % 6 - row % 6 + 6;
      const float* w = m == 0 ? w_each : m == 1 ? w_not : m == 2 ? w_not2 : w_empty;
      if (dr >= 0 && dr < 13) val = w[dr * 13 + dc];
    }
  } else if (id < WS_W2) {                // W1
    int r = id - WS_W1;
    int fi = r >> 3, j = r & 7;
    int l = fi & 63, tk = fi >> 6;
    int ks = tk % 5, ti = tk / 5;
    int row = ti * 16 + (l & 15);
    int k = ks * 32 + (l >> 4) * 8 + j;
    int t = k >> 1; part = k & 1;
    if (row < 100 && t < 72) val = W1[row * 72 + t];
  } else {                                // W2
    int r = id - WS_W2;
    int fi = r >> 3, j = r & 7;
    int l = fi & 63, tk = fi >> 6;
    int ks = tk % 7, ti = tk / 7;
    int row = ti * 16 + (l & 15);
    int k = ks * 32 + (l >> 4) * 8 + j;
    int t = k >> 1; part = k & 1;
    if (row < 100 && t < 100) val = W2[row * 100 + t];
  }
  uint h = f2b(val);
  if (part) { float rem = val - b2f(h); h = f2b(rem); }
  wsp[id] = (ushort)h;
}

// ---------------- async stage: frag table chunk -> LDS buffer via global_load_lds ----------------
template<int NTK, int KW, int KS0, int NKS>
__device__ __forceinline__ void gstage(uint* afb, const ushort* __restrict__ wsp,
                                       int baseU16, int wid, int lane)
{
  const uint4* src = (const uint4*)(wsp + baseU16);
  constexpr int NIT = (NTK * 64 + NT - 1) / NT;
#pragma unroll
  for (int it = 0; it < NIT; ++it) {
    int tk = it * 4 + wid;                // wave-uniform frag-group id
    if (tk < NTK) {
      int ksl = tk % NKS, ti = tk / NKS;  // compile-time NKS -> cheap
      const uint4* gp = src + (ti * KW + KS0 + ksl) * 64 + lane;   // per-lane global
      uint4* lp = (uint4*)afb + tk * 64;                            // wave-uniform LDS base
      __builtin_amdgcn_global_load_lds(
          (const __attribute__((address_space(1))) void*)gp,
          (__attribute__((address_space(3))) void*)lp, 16, 0, 0);
    }
  }
}

template<int NKS, int B0, int NBQ>
__device__ __forceinline__ void fcStep(const uint* sAF, const BU (&Bq)[NBQ],
                                       f32x4 (&Acc)[7], int lane)
{
  const bf16x8* AF = (const bf16x8*)sAF;
#pragma unroll
  for (int ti = 0; ti < 7; ++ti)
#pragma unroll
    for (int ksl = 0; ksl < NKS; ++ksl)
      Acc[ti] = __builtin_amdgcn_mfma_f32_16x16x32_bf16(
          AF[(ti * NKS + ksl) * 64 + lane], Bq[B0 + ksl].v, Acc[ti], 0, 0, 0);
}

// allocator config: (256,2) is the known-good no-spill point (VGPR cap 128, ~108 used).
// occupancy comes from LDS: 52.5 KB -> 3 blocks/CU = 12 waves/CU at runtime.
__global__ __launch_bounds__(NT, 2) void k_main(
    const uint* __restrict__ MKg, const ushort* __restrict__ wsp,
    const float* __restrict__ b_each, const float* __restrict__ b_not,
    const float* __restrict__ b_not2, const float* __restrict__ b_empty,
    const float* __restrict__ b1, const float* __restrict__ b2,
    const float* __restrict__ W3, const float* __restrict__ b3,
    float* __restrict__ out)
{
  __shared__ uint sB[L_TOT];
  const int tid = threadIdx.x;
  const int wid = tid >> 6, lane = tid & 63;
  const int grp = lane >> 4;
  const int bl = wid * 16 + (lane & 15);  // local batch of this lane's B/D columns
  const int gq = grp * 4;

  const float c_each = *b_each, c_not = *b_not, c_not2 = *b_not2, c_empty = *b_empty;
  const float c_b3 = *b3;

  // ---- prologue: biases to LDS, masks straight to registers, stage empty table ----
  if (tid < 112) {
    ((float*)(sB + L_B1))[tid] = (tid < 100) ? b1[tid] : 0.f;
    ((float*)(sB + L_B2))[tid] = (tid < 100) ? b2[tid] : 0.f;
    ((float*)(sB + L_W3))[tid] = (tid < 100) ? W3[tid] : 0.f;
  }
  gstage<25, 5, 0, 5>(sB + L_A, wsp, 3 * 12800, wid, lane);   // empty -> A

  uint mkr[15];
  {
    const int gb = blockIdx.x * NBB + bl;
#pragma unroll
    for (int w = 0; w < 15; ++w) mkr[w] = MKg[w * BN + gb];   // L2-resident, 64B segments
  }
  __syncthreads();

  f32x4 S5[5], A5[5];
  uint zws[5] = {0, 0, 0, 0, 0};

  // ================ empty conv -> S, plus z bytes ================
  gstage<25, 5, 0, 5>(sB + L_B, wsp, 0, wid, lane);           // each -> B
  {
    const bf16x8* AF = (const bf16x8*)(sB + L_A);
    BU Bv[5];
#pragma unroll
    for (int ks = 0; ks < 5; ++ks) {
      uint wv = mkr[0 * 3 + (ks >> 1)];
      int base = ((ks * 16) & 31) + gq;
#pragma unroll
      for (int q = 0; q < 4; ++q)
        Bv[ks].u[q] = ((wv >> (base + q)) & 1u) ? 0x3F803F80u : 0u;
    }
#pragma unroll
    for (int ti = 0; ti < 5; ++ti) {
      f32x4 d = {c_empty, c_empty, c_empty, c_empty};
#pragma unroll
      for (int ks = 0; ks < 5; ++ks) {
        if (ZBLK(ti, ks)) continue;       // exact-zero fragment block
        d = __builtin_amdgcn_mfma_f32_16x16x32_bf16(AF[(ti * 5 + ks) * 64 + lane], Bv[ks].v, d, 0, 0, 0);
      }
      S5[ti] = d;
    }
  }
#pragma unroll
  for (int k = 1; k <= 4; ++k) {
#pragma unroll
    for (int ti = 0; ti < 5; ++ti) {
      uint wv = mkr[k * 3 + (ti >> 1)];
      int base = ((ti * 16) & 31) + gq;
#pragma unroll
      for (int r = 0; r < 4; ++r) {
        float mb = (float)((wv >> (base + r)) & 1u);
        if (S5[ti][r] + mb > 0.f) zws[ti] |= 1u << (r * 8 + (k - 1));
      }
    }
  }
  __syncthreads();                        // each-table staged; empty reads done

  // ================ each convs: S += ecv_k at kind-k cells ================
  // kinds are independent -> process in PAIRS with ks-outer loop: each A-frag
  // read once per pair (100 -> 46 LDS reads). A5 not yet live; ~102 regs.
  gstage<25, 5, 0, 5>(sB + L_A, wsp, 1 * 12800, wid, lane);   // not -> A
  {
    const bf16x8* AF = (const bf16x8*)(sB + L_B);
#pragma unroll 1
    for (int kp = 0; kp < 2; ++kp) {      // kinds (1,2) then (3,4)
      const int k0 = 2 * kp + 1, k1 = 2 * kp + 2;
      f32x4 d0[5], d1[5];
#pragma unroll
      for (int ti = 0; ti < 5; ++ti) {
        d0[ti] = (f32x4){c_each, c_each, c_each, c_each};
        d1[ti] = (f32x4){c_each, c_each, c_each, c_each};
      }
#pragma unroll
      for (int ks = 0; ks < 5; ++ks) {
        BU B0, B1;
        uint wv0 = mkr[k0 * 3 + (ks >> 1)];
        uint wv1 = mkr[k1 * 3 + (ks >> 1)];
        int base = ((ks * 16) & 31) + gq;
#pragma unroll
        for (int q = 0; q < 4; ++q) {
          B0.u[q] = ((wv0 >> (base + q)) & 1u) ? 0x3F803F80u : 0u;
          B1.u[q] = ((wv1 >> (base + q)) & 1u) ? 0x3F803F80u : 0u;
        }
#pragma unroll
        for (int ti = 0; ti < 5; ++ti) {
          if (ZBLK(ti, ks)) continue;
          bf16x8 a = AF[(ti * 5 + ks) * 64 + lane];
          d0[ti] = __builtin_amdgcn_mfma_f32_16x16x32_bf16(a, B0.v, d0[ti], 0, 0, 0);
          d1[ti] = __builtin_amdgcn_mfma_f32_16x16x32_bf16(a, B1.v, d1[ti], 0, 0, 0);
        }
      }
      // merge both kinds (cells disjoint)
#pragma unroll
      for (int ti = 0; ti < 5; ++ti) {
        uint wv0 = mkr[k0 * 3 + (ti >> 1)];
        uint wv1 = mkr[k1 * 3 + (ti >> 1)];
        int base = ((ti * 16) & 31) + gq;
#pragma unroll
        for (int r = 0; r < 4; ++r) {
          if ((wv0 >> (base + r)) & 1u) S5[ti][r] += d0[ti][r];
          if ((wv1 >> (base + r)) & 1u) S5[ti][r] += d1[ti][r];
        }
      }
    }
  }
  // S is CLEAN (empty + ecv_sel); acv init: 0 at empty cells
#pragma unroll
  for (int ti = 0; ti < 5; ++ti) {
    uint wv = mkr[0 * 3 + (ti >> 1)];
    int base = ((ti * 16) & 31) + gq;
#pragma unroll
    for (int r = 0; r < 4; ++r)
      A5[ti][r] = ((wv >> (base + r)) & 1u) ? 0.f : S5[ti][r];
  }
  __syncthreads();                        // not-table staged; each reads done

  // ================ not convs: acv -= not_conv at kind cells (input ~z) ================
  gstage<25, 5, 0, 5>(sB + L_B, wsp, 2 * 12800, wid, lane);   // not2 -> B
  {
    const bf16x8* AF = (const bf16x8*)(sB + L_A);
#pragma unroll 1
    for (int k = 1; k <= 4; ++k) {
      BU Bv[5];
#pragma unroll
      for (int ks = 0; ks < 5; ++ks) {
#pragma unroll
        for (int q = 0; q < 4; ++q)
          Bv[ks].u[q] = ((zws[ks] >> (q * 8 + (k - 1))) & 1u) ? 0u : 0x3F803F80u;
      }
#pragma unroll
      for (int ti = 0; ti < 5; ++ti) {
        f32x4 d = {c_not, c_not, c_not, c_not};
#pragma unroll
        for (int ks = 0; ks < 5; ++ks) {
          if (ZBLK(ti, ks)) continue;
          d = __builtin_amdgcn_mfma_f32_16x16x32_bf16(AF[(ti * 5 + ks) * 64 + lane], Bv[ks].v, d, 0, 0, 0);
        }
        uint wv = mkr[k * 3 + (ti >> 1)];
        int base = ((ti * 16) & 31) + gq;
#pragma unroll
        for (int r = 0; r < 4; ++r)
          if ((wv >> (base + r)) & 1u) A5[ti][r] -= d[r];
      }
    }
  }
  __syncthreads();                        // not2-table staged; not reads done

  // ================ not2 convs (phase C): 4 sequential (acv feedback), register state ================
  gstage<21, 5, 0, 3>(sB + L_A, wsp, WS_W1, wid, lane);       // FC1 chunk a -> A
  {
    const bf16x8* AF = (const bf16x8*)(sB + L_B);
#pragma unroll 1
    for (int k = 1; k <= 4; ++k) {
      BU Bv[5];
#pragma unroll
      for (int ks = 0; ks < 5; ++ks) {
#pragma unroll
        for (int q = 0; q < 4; ++q)
          Bv[ks].u[q] = ((zws[ks] >> (q * 8 + (k - 1))) & 1u) ? 0u : dup_cvt(A5[ks][q]);
      }
#pragma unroll
      for (int ti = 0; ti < 5; ++ti) {
        f32x4 d = {c_not2, c_not2, c_not2, c_not2};
#pragma unroll
        for (int ks = 0; ks < 5; ++ks) {
          if (ZBLK(ti, ks)) continue;
          d = __builtin_amdgcn_mfma_f32_16x16x32_bf16(AF[(ti * 5 + ks) * 64 + lane], Bv[ks].v, d, 0, 0, 0);
        }
        uint wv = mkr[k * 3 + (ti >> 1)];
        int base = ((ti * 16) & 31) + gq;
#pragma unroll
        for (int r = 0; r < 4; ++r)
          if ((wv >> (base + r)) & 1u) A5[ti][r] += S5[ti][r] + d[r];
      }
    }
  }
  __syncthreads();                        // FC1a staged; not2 reads done

  // ================ FC1: h = leaky(W1 x + b1) ================
  BU Bx[5];
#pragma unroll
  for (int ks = 0; ks < 5; ++ks)
#pragma unroll
    for (int q = 0; q < 4; ++q) Bx[ks].u[q] = dup_cvt(A5[ks][q]);
  f32x4 H[7];
#pragma unroll
  for (int ti = 0; ti < 7; ++ti) H[ti] = ((const f32x4*)(sB + L_B1))[ti * 4 + grp];

  gstage<14, 5, 3, 2>(sB + L_B, wsp, WS_W1, wid, lane);       // FC1 chunk b -> B
  fcStep<3, 0>(sB + L_A, Bx, H, lane);
  __syncthreads();
  gstage<21, 7, 0, 3>(sB + L_A, wsp, WS_W2, wid, lane);       // FC2 chunk a -> A
  fcStep<2, 3>(sB + L_B, Bx, H, lane);

  BU By[7];
#pragma unroll
  for (int ti = 0; ti < 7; ++ti) {
#pragma unroll
    for (int r = 0; r < 4; ++r) { float x = H[ti][r]; H[ti][r] = fmaxf(x, 0.2f * x); }
#pragma unroll
    for (int r = 0; r < 4; ++r) By[ti].u[r] = dup_cvt(H[ti][r]);
  }
  f32x4 G[7];
#pragma unroll
  for (int ti = 0; ti < 7; ++ti) G[ti] = ((const f32x4*)(sB + L_B2))[ti * 4 + grp];
  __syncthreads();

  // ================ FC2: g = leaky(W2 h + b2) ================
  gstage<14, 7, 3, 2>(sB + L_B, wsp, WS_W2, wid, lane);       // FC2 chunk b -> B
  fcStep<3, 0>(sB + L_A, By, G, lane);
  __syncthreads();
  gstage<14, 7, 5, 2>(sB + L_A, wsp, WS_W2, wid, lane);       // FC2 chunk c -> A
  fcStep<2, 3>(sB + L_B, By, G, lane);
  __syncthreads();
  fcStep<2, 5>(sB + L_A, By, G, lane);

  // ================ FC3: out = W3 . leaky(g) + b3 ================
  float pd = 0.f;
#pragma unroll
  for (int ti = 0; ti < 7; ++ti) {
    f32x4 w3v = ((const f32x4*)(sB + L_W3))[ti * 4 + grp];
#pragma unroll
    for (int r = 0; r < 4; ++r) {
      float g = G[ti][r];
      g = fmaxf(g, 0.2f * g);
      pd = fmaf(w3v[r], g, pd);
    }
  }
  pd += __shfl_xor(pd, 16);
  pd += __shfl_xor(pd, 32);
  if (lane < 16) out[blockIdx.x * NBB + wid * 16 + lane] = pd + c_b3;
}

extern "C" void kernel_launch(void* const* d_in, const int* in_sizes, int n_in,
                              void* d_out, int out_size, void* d_ws, size_t ws_size,
                              hipStream_t stream)
{
  const int*   dots    = (const int*)d_in[0];
  const float* w_each  = (const float*)d_in[1];
  const float* b_each  = (const float*)d_in[2];
  const float* w_not   = (const float*)d_in[3];
  const float* b_not   = (const float*)d_in[4];
  const float* w_not2  = (const float*)d_in[5];
  const float* b_not2  = (const float*)d_in[6];
  const float* w_empty = (const float*)d_in[7];
  const float* b_empty = (const float*)d_in[8];
  const float* W1 = (const float*)d_in[9];
  const float* b1 = (const float*)d_in[10];
  const float* W2 = (const float*)d_in[11];
  const float* b2 = (const float*)d_in[12];
  const float* W3 = (const float*)d_in[13];
  const float* b3 = (const float*)d_in[14];

  (void)in_sizes; (void)n_in; (void)out_size; (void)ws_size;

  ushort* wsp = (ushort*)d_ws;
  uint*   MKg = (uint*)((char*)d_ws + WS_MK_BYTE);

  k_prep<<<SETUP_BLOCKS + BN / 256, 256, 0, stream>>>(
      w_each, w_not, w_not2, w_empty, W1, W2, dots, wsp, MKg);
  k_main<<<NBLK, NT, 0, stream>>>(
      MKg, wsp, b_each, b_not, b_not2, b_empty, b1, b2, W3, b3, (float*)d_out);
}

// Round 17
// 53.658 us; speedup vs baseline: 3.0296x; 1.0059x over previous
//
#include <hip/hip_runtime.h>

#define BN 65536
#define NT 512            // 8 waves/block: more waves per LDS table copy
#define NBB 128           // batches per block (wave w owns batches w*16..w*16+15)
#define NBLK (BN / NBB)   // 512 blocks (staging L2 traffic halves vs 1024)

typedef unsigned int uint;
typedef unsigned short ushort;
typedef __attribute__((ext_vector_type(8))) short bf16x8;
typedef __attribute__((ext_vector_type(4))) float f32x4;

// LDS layout (u32 units): ping-pong A-frag buffers + biases = 52544 B -> 2 blocks/CU = 16 waves/CU
#define L_A  0        // 6400 (1600 uint4)
#define L_B  6400     // 6400
#define L_B1 12800    // 112 f32
#define L_B2 12912    // 112
#define L_W3 13024    // 112
#define L_TOT 13136

// ws layout: u16 frag tables, then MK u32
// conv mats m*12800 (each=0,not=1,not2=2,empty=3); W1@51200 (7ti x 5ks); W2@69120 (7ti x 7ks)
#define WS_W1 51200
#define WS_W2 69120
#define WS_TOT 94208
#define WS_MK_BYTE 188416          // = WS_TOT*2, 16B aligned
#define SETUP_BLOCKS 368           // ceil(WS_TOT/256)

// statically-zero conv fragment blocks: |board-row gap| > 6 -> outside 13x13 kernel
#define ZBLK(ti, ks) (((ti) == 0 && (ks) == 4) || ((ti) == 4 && (ks) == 0))

__device__ __forceinline__ uint f2b(float f){           // bf16 rne bits
  uint u = __float_as_uint(f);
  return (u + 0x7FFFu + ((u >> 16) & 1u)) >> 16;
}
__device__ __forceinline__ float b2f(uint h){ return __uint_as_float(h << 16); }
__device__ __forceinline__ uint dup_cvt(float f){       // packed bf16 dup via HW cvt (RNE)
  uint r;
  asm("v_cvt_pk_bf16_f32 %0, %1, %2" : "=v"(r) : "v"(f), "v"(f));
  return r;
}

union BU { uint u[4]; bf16x8 v; };

// ---------------- prep: frag tables + per-batch kind bitmasks (fused) ----------------
__global__ __launch_bounds__(256) void k_prep(
    const float* __restrict__ w_each, const float* __restrict__ w_not,
    const float* __restrict__ w_not2, const float* __restrict__ w_empty,
    const float* __restrict__ W1, const float* __restrict__ W2,
    const int* __restrict__ dots,
    ushort* __restrict__ wsp, uint* __restrict__ MKg)
{
  if (blockIdx.x >= SETUP_BLOCKS) {       // mask-building blocks
    int b = (blockIdx.x - SETUP_BLOCKS) * 256 + threadIdx.x;
    uint mk[5][3] = {};
#pragma unroll
    for (int c = 0; c < 72; ++c) {
      int v = dots[c * BN + b];
#pragma unroll
      for (int k = 0; k < 5; ++k)
        mk[k][c >> 5] |= (uint)(v == k) << (c & 31);
    }
#pragma unroll
    for (int k = 0; k < 5; ++k)
#pragma unroll
      for (int w = 0; w < 3; ++w)
        MKg[(k * 3 + w) * BN + b] = mk[k][w];
    return;
  }
  int id = blockIdx.x * 256 + threadIdx.x;
  if (id >= WS_TOT) return;
  float val = 0.f;
  int part;
  if (id < 51200) {                       // conv mats
    int m = id / 12800, r = id % 12800;
    int fi = r >> 3, j = r & 7;
    int l = fi & 63, tk = fi >> 6;
    int ks = tk % 5, ti = tk / 5;
    int row = ti * 16 + (l & 15);         // output cell
    int k = ks * 32 + (l >> 4) * 8 + j;
    int t = k >> 1; part = k & 1;         // input cell, hi/lo slot
    if (row < 72 && t < 72) {
      int dr = t / 6 - row / 6 + 6, dc = t % 6 - row % 6 + 6;
      const float* w = m == 0 ? w_each : m == 1 ? w_not : m == 2 ? w_not2 : w_empty;
      if (dr >= 0 && dr < 13) val = w[dr * 13 + dc];
    }
  } else if (id < WS_W2) {                // W1
    int r = id - WS_W1;
    int fi = r >> 3, j = r & 7;
    int l = fi & 63, tk = fi >> 6;
    int ks = tk % 5, ti = tk / 5;
    int row = ti * 16 + (l & 15);
    int k = ks * 32 + (l >> 4) * 8 + j;
    int t = k >> 1; part = k & 1;
    if (row < 100 && t < 72) val = W1[row * 72 + t];
  } else {                                // W2
    int r = id - WS_W2;
    int fi = r >> 3, j = r & 7;
    int l = fi & 63, tk = fi >> 6;
    int ks = tk % 7, ti = tk / 7;
    int row = ti * 16 + (l & 15);
    int k = ks * 32 + (l >> 4) * 8 + j;
    int t = k >> 1; part = k & 1;
    if (row < 100 && t < 100) val = W2[row * 100 + t];
  }
  uint h = f2b(val);
  if (part) { float rem = val - b2f(h); h = f2b(rem); }
  wsp[id] = (ushort)h;
}

// ---------------- async stage: frag table chunk -> LDS buffer via global_load_lds ----------------
template<int NTK, int KW, int KS0, int NKS>
__device__ __forceinline__ void gstage(uint* afb, const ushort* __restrict__ wsp,
                                       int baseU16, int wid, int lane)
{
  const uint4* src = (const uint4*)(wsp + baseU16);
  constexpr int NW = NT / 64;
  constexpr int NIT = (NTK + NW - 1) / NW;
#pragma unroll
  for (int it = 0; it < NIT; ++it) {
    int tk = it * NW + wid;               // wave-uniform frag-group id
    if (tk < NTK) {
      int ksl = tk % NKS, ti = tk / NKS;  // compile-time NKS -> cheap
      const uint4* gp = src + (ti * KW + KS0 + ksl) * 64 + lane;   // per-lane global
      uint4* lp = (uint4*)afb + tk * 64;                            // wave-uniform LDS base
      __builtin_amdgcn_global_load_lds(
          (const __attribute__((address_space(1))) void*)gp,
          (__attribute__((address_space(3))) void*)lp, 16, 0, 0);
    }
  }
}

template<int NKS, int B0, int NBQ>
__device__ __forceinline__ void fcStep(const uint* sAF, const BU (&Bq)[NBQ],
                                       f32x4 (&Acc)[7], int lane)
{
  const bf16x8* AF = (const bf16x8*)sAF;
#pragma unroll
  for (int ti = 0; ti < 7; ++ti)
#pragma unroll
    for (int ksl = 0; ksl < NKS; ++ksl)
      Acc[ti] = __builtin_amdgcn_mfma_f32_16x16x32_bf16(
          AF[(ti * NKS + ksl) * 64 + lane], Bq[B0 + ksl].v, Acc[ti], 0, 0, 0);
}

// allocator: empirical cap = 256/arg2 regs ((256,2)->128, (512,4)->64, wpe(4,4)->64).
// (512,2) should give cap 128 >= ~116 live -> no spill, 16 waves/CU.
__global__ __launch_bounds__(NT, 2) void k_main(
    const uint* __restrict__ MKg, const ushort* __restrict__ wsp,
    const float* __restrict__ b_each, const float* __restrict__ b_not,
    const float* __restrict__ b_not2, const float* __restrict__ b_empty,
    const float* __restrict__ b1, const float* __restrict__ b2,
    const float* __restrict__ W3, const float* __restrict__ b3,
    float* __restrict__ out)
{
  __shared__ uint sB[L_TOT];
  const int tid = threadIdx.x;
  const int wid = tid >> 6, lane = tid & 63;
  const int grp = lane >> 4;
  const int bl = wid * 16 + (lane & 15);  // local batch of this lane's B/D columns (0..127)
  const int gq = grp * 4;

  const float c_each = *b_each, c_not = *b_not, c_not2 = *b_not2, c_empty = *b_empty;
  const float c_b3 = *b3;

  // ---- prologue: biases to LDS, masks straight to registers, stage empty table ----
  if (tid < 112) {
    ((float*)(sB + L_B1))[tid] = (tid < 100) ? b1[tid] : 0.f;
    ((float*)(sB + L_B2))[tid] = (tid < 100) ? b2[tid] : 0.f;
    ((float*)(sB + L_W3))[tid] = (tid < 100) ? W3[tid] : 0.f;
  }
  gstage<25, 5, 0, 5>(sB + L_A, wsp, 3 * 12800, wid, lane);   // empty -> A

  uint mkr[15];
  {
    const int gb = blockIdx.x * NBB + bl;
#pragma unroll
    for (int w = 0; w < 15; ++w) mkr[w] = MKg[w * BN + gb];   // L2-resident, 64B segments
  }
  __syncthreads();

  f32x4 S5[5], A5[5];
  uint zws[5] = {0, 0, 0, 0, 0};

  // ================ empty conv -> S, plus z bytes ================
  gstage<25, 5, 0, 5>(sB + L_B, wsp, 0, wid, lane);           // each -> B
  {
    const bf16x8* AF = (const bf16x8*)(sB + L_A);
    BU Bv[5];
#pragma unroll
    for (int ks = 0; ks < 5; ++ks) {
      uint wv = mkr[0 * 3 + (ks >> 1)];
      int base = ((ks * 16) & 31) + gq;
#pragma unroll
      for (int q = 0; q < 4; ++q)
        Bv[ks].u[q] = ((wv >> (base + q)) & 1u) ? 0x3F803F80u : 0u;
    }
#pragma unroll
    for (int ti = 0; ti < 5; ++ti) {
      f32x4 d = {c_empty, c_empty, c_empty, c_empty};
#pragma unroll
      for (int ks = 0; ks < 5; ++ks) {
        if (ZBLK(ti, ks)) continue;       // exact-zero fragment block
        d = __builtin_amdgcn_mfma_f32_16x16x32_bf16(AF[(ti * 5 + ks) * 64 + lane], Bv[ks].v, d, 0, 0, 0);
      }
      S5[ti] = d;
    }
  }
#pragma unroll
  for (int k = 1; k <= 4; ++k) {
#pragma unroll
    for (int ti = 0; ti < 5; ++ti) {
      uint wv = mkr[k * 3 + (ti >> 1)];
      int base = ((ti * 16) & 31) + gq;
#pragma unroll
      for (int r = 0; r < 4; ++r) {
        float mb = (float)((wv >> (base + r)) & 1u);
        if (S5[ti][r] + mb > 0.f) zws[ti] |= 1u << (r * 8 + (k - 1));
      }
    }
  }
  __syncthreads();                        // each-table staged; empty reads done

  // ================ each convs: S += ecv_k at kind-k cells ================
  // kinds independent -> PAIRS with ks-outer loop: each A-frag read once per pair.
  gstage<25, 5, 0, 5>(sB + L_A, wsp, 1 * 12800, wid, lane);   // not -> A
  {
    const bf16x8* AF = (const bf16x8*)(sB + L_B);
#pragma unroll 1
    for (int kp = 0; kp < 2; ++kp) {      // kinds (1,2) then (3,4)
      const int k0 = 2 * kp + 1, k1 = 2 * kp + 2;
      f32x4 d0[5], d1[5];
#pragma unroll
      for (int ti = 0; ti < 5; ++ti) {
        d0[ti] = (f32x4){c_each, c_each, c_each, c_each};
        d1[ti] = (f32x4){c_each, c_each, c_each, c_each};
      }
#pragma unroll
      for (int ks = 0; ks < 5; ++ks) {
        BU B0, B1;
        uint wv0 = mkr[k0 * 3 + (ks >> 1)];
        uint wv1 = mkr[k1 * 3 + (ks >> 1)];
        int base = ((ks * 16) & 31) + gq;
#pragma unroll
        for (int q = 0; q < 4; ++q) {
          B0.u[q] = ((wv0 >> (base + q)) & 1u) ? 0x3F803F80u : 0u;
          B1.u[q] = ((wv1 >> (base + q)) & 1u) ? 0x3F803F80u : 0u;
        }
#pragma unroll
        for (int ti = 0; ti < 5; ++ti) {
          if (ZBLK(ti, ks)) continue;
          bf16x8 a = AF[(ti * 5 + ks) * 64 + lane];
          d0[ti] = __builtin_amdgcn_mfma_f32_16x16x32_bf16(a, B0.v, d0[ti], 0, 0, 0);
          d1[ti] = __builtin_amdgcn_mfma_f32_16x16x32_bf16(a, B1.v, d1[ti], 0, 0, 0);
        }
      }
      // merge both kinds (cells disjoint)
#pragma unroll
      for (int ti = 0; ti < 5; ++ti) {
        uint wv0 = mkr[k0 * 3 + (ti >> 1)];
        uint wv1 = mkr[k1 * 3 + (ti >> 1)];
        int base = ((ti * 16) & 31) + gq;
#pragma unroll
        for (int r = 0; r < 4; ++r) {
          if ((wv0 >> (base + r)) & 1u) S5[ti][r] += d0[ti][r];
          if ((wv1 >> (base + r)) & 1u) S5[ti][r] += d1[ti][r];
        }
      }
    }
  }
  // S is CLEAN (empty + ecv_sel); acv init: 0 at empty cells
#pragma unroll
  for (int ti = 0; ti < 5; ++ti) {
    uint wv = mkr[0 * 3 + (ti >> 1)];
    int base = ((ti * 16) & 31) + gq;
#pragma unroll
    for (int r = 0; r < 4; ++r)
      A5[ti][r] = ((wv >> (base + r)) & 1u) ? 0.f : S5[ti][r];
  }
  __syncthreads();                        // not-table staged; each reads done

  // ================ not convs: acv -= not_conv at kind cells (input ~z) ================
  gstage<25, 5, 0, 5>(sB + L_B, wsp, 2 * 12800, wid, lane);   // not2 -> B
  {
    const bf16x8* AF = (const bf16x8*)(sB + L_A);
#pragma unroll 1
    for (int k = 1; k <= 4; ++k) {
      BU Bv[5];
#pragma unroll
      for (int ks = 0; ks < 5; ++ks) {
#pragma unroll
        for (int q = 0; q < 4; ++q)
          Bv[ks].u[q] = ((zws[ks] >> (q * 8 + (k - 1))) & 1u) ? 0u : 0x3F803F80u;
      }
#pragma unroll
      for (int ti = 0; ti < 5; ++ti) {
        f32x4 d = {c_not, c_not, c_not, c_not};
#pragma unroll
        for (int ks = 0; ks < 5; ++ks) {
          if (ZBLK(ti, ks)) continue;
          d = __builtin_amdgcn_mfma_f32_16x16x32_bf16(AF[(ti * 5 + ks) * 64 + lane], Bv[ks].v, d, 0, 0, 0);
        }
        uint wv = mkr[k * 3 + (ti >> 1)];
        int base = ((ti * 16) & 31) + gq;
#pragma unroll
        for (int r = 0; r < 4; ++r)
          if ((wv >> (base + r)) & 1u) A5[ti][r] -= d[r];
      }
    }
  }
  __syncthreads();                        // not2-table staged; not reads done

  // ================ not2 convs (phase C): 4 sequential (acv feedback), register state ================
  gstage<21, 5, 0, 3>(sB + L_A, wsp, WS_W1, wid, lane);       // FC1 chunk a -> A
  {
    const bf16x8* AF = (const bf16x8*)(sB + L_B);
#pragma unroll 1
    for (int k = 1; k <= 4; ++k) {
      BU Bv[5];
#pragma unroll
      for (int ks = 0; ks < 5; ++ks) {
#pragma unroll
        for (int q = 0; q < 4; ++q)
          Bv[ks].u[q] = ((zws[ks] >> (q * 8 + (k - 1))) & 1u) ? 0u : dup_cvt(A5[ks][q]);
      }
#pragma unroll
      for (int ti = 0; ti < 5; ++ti) {
        f32x4 d = {c_not2, c_not2, c_not2, c_not2};
#pragma unroll
        for (int ks = 0; ks < 5; ++ks) {
          if (ZBLK(ti, ks)) continue;
          d = __builtin_amdgcn_mfma_f32_16x16x32_bf16(AF[(ti * 5 + ks) * 64 + lane], Bv[ks].v, d, 0, 0, 0);
        }
        uint wv = mkr[k * 3 + (ti >> 1)];
        int base = ((ti * 16) & 31) + gq;
#pragma unroll
        for (int r = 0; r < 4; ++r)
          if ((wv >> (base + r)) & 1u) A5[ti][r] += S5[ti][r] + d[r];
      }
    }
  }
  __syncthreads();                        // FC1a staged; not2 reads done

  // ================ FC1: h = leaky(W1 x + b1) ================
  BU Bx[5];
#pragma unroll
  for (int ks = 0; ks < 5; ++ks)
#pragma unroll
    for (int q = 0; q < 4; ++q) Bx[ks].u[q] = dup_cvt(A5[ks][q]);
  f32x4 H[7];
#pragma unroll
  for (int ti = 0; ti < 7; ++ti) H[ti] = ((const f32x4*)(sB + L_B1))[ti * 4 + grp];

  gstage<14, 5, 3, 2>(sB + L_B, wsp, WS_W1, wid, lane);       // FC1 chunk b -> B
  fcStep<3, 0>(sB + L_A, Bx, H, lane);
  __syncthreads();
  gstage<21, 7, 0, 3>(sB + L_A, wsp, WS_W2, wid, lane);       // FC2 chunk a -> A
  fcStep<2, 3>(sB + L_B, Bx, H, lane);

  BU By[7];
#pragma unroll
  for (int ti = 0; ti < 7; ++ti) {
#pragma unroll
    for (int r = 0; r < 4; ++r) { float x = H[ti][r]; H[ti][r] = fmaxf(x, 0.2f * x); }
#pragma unroll
    for (int r = 0; r < 4; ++r) By[ti].u[r] = dup_cvt(H[ti][r]);
  }
  f32x4 G[7];
#pragma unroll
  for (int ti = 0; ti < 7; ++ti) G[ti] = ((const f32x4*)(sB + L_B2))[ti * 4 + grp];
  __syncthreads();

  // ================ FC2: g = leaky(W2 h + b2) ================
  gstage<14, 7, 3, 2>(sB + L_B, wsp, WS_W2, wid, lane);       // FC2 chunk b -> B
  fcStep<3, 0>(sB + L_A, By, G, lane);
  __syncthreads();
  gstage<14, 7, 5, 2>(sB + L_A, wsp, WS_W2, wid, lane);       // FC2 chunk c -> A
  fcStep<2, 3>(sB + L_B, By, G, lane);
  __syncthreads();
  fcStep<2, 5>(sB + L_A, By, G, lane);

  // ================ FC3: out = W3 . leaky(g) + b3 ================
  float pd = 0.f;
#pragma unroll
  for (int ti = 0; ti < 7; ++ti) {
    f32x4 w3v = ((const f32x4*)(sB + L_W3))[ti * 4 + grp];
#pragma unroll
    for (int r = 0; r < 4; ++r) {
      float g = G[ti][r];
      g = fmaxf(g, 0.2f * g);
      pd = fmaf(w3v[r], g, pd);
    }
  }
  pd += __shfl_xor(pd, 16);
  pd += __shfl_xor(pd, 32);
  if (lane < 16) out[blockIdx.x * NBB + wid * 16 + lane] = pd + c_b3;
}

extern "C" void kernel_launch(void* const* d_in, const int* in_sizes, int n_in,
                              void* d_out, int out_size, void* d_ws, size_t ws_size,
                              hipStream_t stream)
{
  const int*   dots    = (const int*)d_in[0];
  const float* w_each  = (const float*)d_in[1];
  const float* b_each  = (const float*)d_in[2];
  const float* w_not   = (const float*)d_in[3];
  const float* b_not   = (const float*)d_in[4];
  const float* w_not2  = (const float*)d_in[5];
  const float* b_not2  = (const float*)d_in[6];
  const float* w_empty = (const float*)d_in[7];
  const float* b_empty = (const float*)d_in[8];
  const float* W1 = (const float*)d_in[9];
  const float* b1 = (const float*)d_in[10];
  const float* W2 = (const float*)d_in[11];
  const float* b2 = (const float*)d_in[12];
  const float* W3 = (const float*)d_in[13];
  const float* b3 = (const float*)d_in[14];

  (void)in_sizes; (void)n_in; (void)out_size; (void)ws_size;

  ushort* wsp = (ushort*)d_ws;
  uint*   MKg = (uint*)((char*)d_ws + WS_MK_BYTE);

  k_prep<<<SETUP_BLOCKS + BN / 256, 256, 0, stream>>>(
      w_each, w_not, w_not2, w_empty, W1, W2, dots, wsp, MKg);
  k_main<<<NBLK, NT, 0, stream>>>(
      MKg, wsp, b_each, b_not, b_not2, b_empty, b1, b2, W3, b3, (float*)d_out);
}

// Round 19
// 53.096 us; speedup vs baseline: 3.0617x; 1.0106x over previous
//
#include <hip/hip_runtime.h>

#define BN 65536
#define NT 512            // 8 waves/block: more waves per LDS table copy
#define NBB 128           // batches per block (wave w owns batches w*16..w*16+15)
#define NBLK (BN / NBB)   // 512 blocks (staging L2 traffic halves vs 1024)

typedef unsigned int uint;
typedef unsigned short ushort;
typedef __attribute__((ext_vector_type(8))) short bf16x8;
typedef __attribute__((ext_vector_type(4))) float f32x4;

// LDS layout (u32 units): ping-pong A-frag buffers + biases = 52544 B -> 2 blocks/CU = 16 waves/CU
#define L_A  0        // 6400 (1600 uint4)
#define L_B  6400     // 6400
#define L_B1 12800    // 112 f32
#define L_B2 12912    // 112
#define L_W3 13024    // 112
#define L_TOT 13136

// ws layout: u16 frag tables, then MK u32
// conv mats m*12800 (each=0,not=1,not2=2,empty=3); W1@51200 (7ti x 5ks); W2@69120 (7ti x 7ks)
#define WS_W1 51200
#define WS_W2 69120
#define WS_TOT 94208
#define WS_MK_BYTE 188416          // = WS_TOT*2, 16B aligned
#define SETUP_BLOCKS 368           // ceil(WS_TOT/256)

// statically-zero conv fragment blocks: |board-row gap| > 6 -> outside 13x13 kernel
#define ZBLK(ti, ks) (((ti) == 0 && (ks) == 4) || ((ti) == 4 && (ks) == 0))

__device__ __forceinline__ uint f2b(float f){           // bf16 rne bits
  uint u = __float_as_uint(f);
  return (u + 0x7FFFu + ((u >> 16) & 1u)) >> 16;
}
__device__ __forceinline__ float b2f(uint h){ return __uint_as_float(h << 16); }
__device__ __forceinline__ uint dup_cvt(float f){       // packed bf16 dup via HW cvt (RNE)
  uint r;
  asm("v_cvt_pk_bf16_f32 %0, %1, %2" : "=v"(r) : "v"(f), "v"(f));
  return r;
}

union BU { uint u[4]; bf16x8 v; };

// ---------------- prep: frag tables + per-batch kind bitmasks (fused) ----------------
__global__ __launch_bounds__(256) void k_prep(
    const float* __restrict__ w_each, const float* __restrict__ w_not,
    const float* __restrict__ w_not2, const float* __restrict__ w_empty,
    const float* __restrict__ W1, const float* __restrict__ W2,
    const int* __restrict__ dots,
    ushort* __restrict__ wsp, uint* __restrict__ MKg)
{
  if (blockIdx.x >= SETUP_BLOCKS) {       // mask-building blocks
    int b = (blockIdx.x - SETUP_BLOCKS) * 256 + threadIdx.x;
    uint mk[5][3] = {};
#pragma unroll
    for (int c = 0; c < 72; ++c) {
      int v = dots[c * BN + b];
#pragma unroll
      for (int k = 0; k < 5; ++k)
        mk[k][c >> 5] |= (uint)(v == k) << (c & 31);
    }
#pragma unroll
    for (int k = 0; k < 5; ++k)
#pragma unroll
      for (int w = 0; w < 3; ++w)
        MKg[(k * 3 + w) * BN + b] = mk[k][w];
    return;
  }
  int id = blockIdx.x * 256 + threadIdx.x;
  if (id >= WS_TOT) return;
  float val = 0.f;
  int part;
  if (id < 51200) {                       // conv mats
    int m = id / 12800, r = id % 12800;
    int fi = r >> 3, j = r & 7;
    int l = fi & 63, tk = fi >> 6;
    int ks = tk % 5, ti = tk / 5;
    int row = ti * 16 + (l & 15);         // output cell
    int k = ks * 32 + (l >> 4) * 8 + j;
    int t = k >> 1; part = k & 1;         // input cell, hi/lo slot
    if (row < 72 && t < 72) {
      int dr = t / 6 - row / 6 + 6, dc = t % 6 - row % 6 + 6;
      const float* w = m == 0 ? w_each : m == 1 ? w_not : m == 2 ? w_not2 : w_empty;
      if (dr >= 0 && dr < 13) val = w[dr * 13 + dc];
    }
  } else if (id < WS_W2) {                // W1
    int r = id - WS_W1;
    int fi = r >> 3, j = r & 7;
    int l = fi & 63, tk = fi >> 6;
    int ks = tk % 5, ti = tk / 5;
    int row = ti * 16 + (l & 15);
    int k = ks * 32 + (l >> 4) * 8 + j;
    int t = k >> 1; part = k & 1;
    if (row < 100 && t < 72) val = W1[row * 72 + t];
  } else {                                // W2
    int r = id - WS_W2;
    int fi = r >> 3, j = r & 7;
    int l = fi & 63, tk = fi >> 6;
    int ks = tk % 7, ti = tk / 7;
    int row = ti * 16 + (l & 15);
    int k = ks * 32 + (l >> 4) * 8 + j;
    int t = k >> 1; part = k & 1;
    if (row < 100 && t < 100) val = W2[row * 100 + t];
  }
  uint h = f2b(val);
  if (part) { float rem = val - b2f(h); h = f2b(rem); }
  wsp[id] = (ushort)h;
}

// ---------------- async stage: frag table chunk -> LDS buffer via global_load_lds ----------------
template<int NTK, int KW, int KS0, int NKS>
__device__ __forceinline__ void gstage(uint* afb, const ushort* __restrict__ wsp,
                                       int baseU16, int wid, int lane)
{
  const uint4* src = (const uint4*)(wsp + baseU16);
  constexpr int NW = NT / 64;
  constexpr int NIT = (NTK + NW - 1) / NW;
#pragma unroll
  for (int it = 0; it < NIT; ++it) {
    int tk = it * NW + wid;               // wave-uniform frag-group id
    if (tk < NTK) {
      int ksl = tk % NKS, ti = tk / NKS;  // compile-time NKS -> cheap
      const uint4* gp = src + (ti * KW + KS0 + ksl) * 64 + lane;   // per-lane global
      uint4* lp = (uint4*)afb + tk * 64;                            // wave-uniform LDS base
      __builtin_amdgcn_global_load_lds(
          (const __attribute__((address_space(1))) void*)gp,
          (__attribute__((address_space(3))) void*)lp, 16, 0, 0);
    }
  }
}

template<int NKS, int B0, int NBQ>
__device__ __forceinline__ void fcStep(const uint* sAF, const BU (&Bq)[NBQ],
                                       f32x4 (&Acc)[7], int lane)
{
  const bf16x8* AF = (const bf16x8*)sAF;
#pragma unroll
  for (int ti = 0; ti < 7; ++ti)
#pragma unroll
    for (int ksl = 0; ksl < NKS; ++ksl)
      Acc[ti] = __builtin_amdgcn_mfma_f32_16x16x32_bf16(
          AF[(ti * NKS + ksl) * 64 + lane], Bq[B0 + ksl].v, Acc[ti], 0, 0, 0);
}

// allocator: empirical cap = 256/arg2 regs ((256,2)->128, (512,4)->64, wpe(4,4)->64).
// (512,2) gives cap 128 >= ~116 live -> no spill, 16 waves/CU.
__global__ __launch_bounds__(NT, 2) void k_main(
    const uint* __restrict__ MKg, const ushort* __restrict__ wsp,
    const float* __restrict__ b_each, const float* __restrict__ b_not,
    const float* __restrict__ b_not2, const float* __restrict__ b_empty,
    const float* __restrict__ b1, const float* __restrict__ b2,
    const float* __restrict__ W3, const float* __restrict__ b3,
    float* __restrict__ out)
{
  __shared__ uint sB[L_TOT];
  const int tid = threadIdx.x;
  const int wid = tid >> 6, lane = tid & 63;
  const int grp = lane >> 4;
  const int bl = wid * 16 + (lane & 15);  // local batch of this lane's B/D columns (0..127)
  const int gq = grp * 4;

  const float c_each = *b_each, c_not = *b_not, c_not2 = *b_not2, c_empty = *b_empty;
  const float c_b3 = *b3;

  // ---- prologue: biases to LDS, masks straight to registers, stage empty table ----
  if (tid < 112) {
    ((float*)(sB + L_B1))[tid] = (tid < 100) ? b1[tid] : 0.f;
    ((float*)(sB + L_B2))[tid] = (tid < 100) ? b2[tid] : 0.f;
    ((float*)(sB + L_W3))[tid] = (tid < 100) ? W3[tid] : 0.f;
  }
  gstage<25, 5, 0, 5>(sB + L_A, wsp, 3 * 12800, wid, lane);   // empty -> A

  uint mkr[15];
  {
    const int gb = blockIdx.x * NBB + bl;
#pragma unroll
    for (int w = 0; w < 15; ++w) mkr[w] = MKg[w * BN + gb];   // L2-resident, 64B segments
  }
  __syncthreads();

  f32x4 S5[5], A5[5];
  uint zws[5] = {0, 0, 0, 0, 0};

  // ================ empty conv -> S, plus z bytes ================
  gstage<25, 5, 0, 5>(sB + L_B, wsp, 0, wid, lane);           // each -> B
  {
    const bf16x8* AF = (const bf16x8*)(sB + L_A);
    BU Bv[5];
#pragma unroll
    for (int ks = 0; ks < 5; ++ks) {
      uint wv = mkr[0 * 3 + (ks >> 1)];
      int base = ((ks * 16) & 31) + gq;
#pragma unroll
      for (int q = 0; q < 4; ++q)
        Bv[ks].u[q] = ((wv >> (base + q)) & 1u) ? 0x3F803F80u : 0u;
    }
#pragma unroll
    for (int ti = 0; ti < 5; ++ti) {
      f32x4 d = {c_empty, c_empty, c_empty, c_empty};
#pragma unroll
      for (int ks = 0; ks < 5; ++ks) {
        if (ZBLK(ti, ks)) continue;       // exact-zero fragment block
        d = __builtin_amdgcn_mfma_f32_16x16x32_bf16(AF[(ti * 5 + ks) * 64 + lane], Bv[ks].v, d, 0, 0, 0);
      }
      S5[ti] = d;
    }
  }
#pragma unroll
  for (int k = 1; k <= 4; ++k) {
#pragma unroll
    for (int ti = 0; ti < 5; ++ti) {
      uint wv = mkr[k * 3 + (ti >> 1)];
      int base = ((ti * 16) & 31) + gq;
#pragma unroll
      for (int r = 0; r < 4; ++r) {
        float mb = (float)((wv >> (base + r)) & 1u);
        if (S5[ti][r] + mb > 0.f) zws[ti] |= 1u << (r * 8 + (k - 1));
      }
    }
  }
  __syncthreads();                        // each-table staged; empty reads done

  // ================ each convs: S += ecv_k at kind-k cells ================
  // kinds independent -> PAIRS with ks-outer loop: each A-frag read once per pair.
  gstage<25, 5, 0, 5>(sB + L_A, wsp, 1 * 12800, wid, lane);   // not -> A
  {
    const bf16x8* AF = (const bf16x8*)(sB + L_B);
#pragma unroll 1
    for (int kp = 0; kp < 2; ++kp) {      // kinds (1,2) then (3,4)
      const int k0 = 2 * kp + 1, k1 = 2 * kp + 2;
      f32x4 d0[5], d1[5];
#pragma unroll
      for (int ti = 0; ti < 5; ++ti) {
        d0[ti] = (f32x4){c_each, c_each, c_each, c_each};
        d1[ti] = (f32x4){c_each, c_each, c_each, c_each};
      }
#pragma unroll
      for (int ks = 0; ks < 5; ++ks) {
        BU B0, B1;
        uint wv0 = mkr[k0 * 3 + (ks >> 1)];
        uint wv1 = mkr[k1 * 3 + (ks >> 1)];
        int base = ((ks * 16) & 31) + gq;
#pragma unroll
        for (int q = 0; q < 4; ++q) {
          B0.u[q] = ((wv0 >> (base + q)) & 1u) ? 0x3F803F80u : 0u;
          B1.u[q] = ((wv1 >> (base + q)) & 1u) ? 0x3F803F80u : 0u;
        }
#pragma unroll
        for (int ti = 0; ti < 5; ++ti) {
          if (ZBLK(ti, ks)) continue;
          bf16x8 a = AF[(ti * 5 + ks) * 64 + lane];
          d0[ti] = __builtin_amdgcn_mfma_f32_16x16x32_bf16(a, B0.v, d0[ti], 0, 0, 0);
          d1[ti] = __builtin_amdgcn_mfma_f32_16x16x32_bf16(a, B1.v, d1[ti], 0, 0, 0);
        }
      }
      // merge both kinds (cells disjoint)
#pragma unroll
      for (int ti = 0; ti < 5; ++ti) {
        uint wv0 = mkr[k0 * 3 + (ti >> 1)];
        uint wv1 = mkr[k1 * 3 + (ti >> 1)];
        int base = ((ti * 16) & 31) + gq;
#pragma unroll
        for (int r = 0; r < 4; ++r) {
          if ((wv0 >> (base + r)) & 1u) S5[ti][r] += d0[ti][r];
          if ((wv1 >> (base + r)) & 1u) S5[ti][r] += d1[ti][r];
        }
      }
    }
  }
  // S is CLEAN (empty + ecv_sel); acv init: 0 at empty cells
#pragma unroll
  for (int ti = 0; ti < 5; ++ti) {
    uint wv = mkr[0 * 3 + (ti >> 1)];
    int base = ((ti * 16) & 31) + gq;
#pragma unroll
    for (int r = 0; r < 4; ++r)
      A5[ti][r] = ((wv >> (base + r)) & 1u) ? 0.f : S5[ti][r];
  }
  __syncthreads();                        // not-table staged; each reads done

  // ================ not convs: acv -= not_conv at kind cells (input ~z) ================
  gstage<25, 5, 0, 5>(sB + L_B, wsp, 2 * 12800, wid, lane);   // not2 -> B
  {
    const bf16x8* AF = (const bf16x8*)(sB + L_A);
#pragma unroll 1
    for (int k = 1; k <= 4; ++k) {
      BU Bv[5];
#pragma unroll
      for (int ks = 0; ks < 5; ++ks) {
#pragma unroll
        for (int q = 0; q < 4; ++q)
          Bv[ks].u[q] = ((zws[ks] >> (q * 8 + (k - 1))) & 1u) ? 0u : 0x3F803F80u;
      }
#pragma unroll
      for (int ti = 0; ti < 5; ++ti) {
        f32x4 d = {c_not, c_not, c_not, c_not};
#pragma unroll
        for (int ks = 0; ks < 5; ++ks) {
          if (ZBLK(ti, ks)) continue;
          d = __builtin_amdgcn_mfma_f32_16x16x32_bf16(AF[(ti * 5 + ks) * 64 + lane], Bv[ks].v, d, 0, 0, 0);
        }
        uint wv = mkr[k * 3 + (ti >> 1)];
        int base = ((ti * 16) & 31) + gq;
#pragma unroll
        for (int r = 0; r < 4; ++r)
          if ((wv >> (base + r)) & 1u) A5[ti][r] -= d[r];
      }
    }
  }
  __syncthreads();                        // not2-table staged; not reads done

  // ================ not2 convs (phase C): 4 sequential (acv feedback), register state ================
  gstage<21, 5, 0, 3>(sB + L_A, wsp, WS_W1, wid, lane);       // FC1 chunk a -> A
  {
    const bf16x8* AF = (const bf16x8*)(sB + L_B);
#pragma unroll 1
    for (int k = 1; k <= 4; ++k) {
      BU Bv[5];
#pragma unroll
      for (int ks = 0; ks < 5; ++ks) {
#pragma unroll
        for (int q = 0; q < 4; ++q)
          Bv[ks].u[q] = ((zws[ks] >> (q * 8 + (k - 1))) & 1u) ? 0u : dup_cvt(A5[ks][q]);
      }
#pragma unroll
      for (int ti = 0; ti < 5; ++ti) {
        f32x4 d = {c_not2, c_not2, c_not2, c_not2};
#pragma unroll
        for (int ks = 0; ks < 5; ++ks) {
          if (ZBLK(ti, ks)) continue;
          d = __builtin_amdgcn_mfma_f32_16x16x32_bf16(AF[(ti * 5 + ks) * 64 + lane], Bv[ks].v, d, 0, 0, 0);
        }
        uint wv = mkr[k * 3 + (ti >> 1)];
        int base = ((ti * 16) & 31) + gq;
#pragma unroll
        for (int r = 0; r < 4; ++r)
          if ((wv >> (base + r)) & 1u) A5[ti][r] += S5[ti][r] + d[r];
      }
    }
  }
  __syncthreads();                        // FC1a staged; not2 reads done

  // ================ FC1: h = leaky(W1 x + b1) ================
  BU Bx[5];
#pragma unroll
  for (int ks = 0; ks < 5; ++ks)
#pragma unroll
    for (int q = 0; q < 4; ++q) Bx[ks].u[q] = dup_cvt(A5[ks][q]);
  f32x4 H[7];
#pragma unroll
  for (int ti = 0; ti < 7; ++ti) H[ti] = ((const f32x4*)(sB + L_B1))[ti * 4 + grp];

  gstage<14, 5, 3, 2>(sB + L_B, wsp, WS_W1, wid, lane);       // FC1 chunk b -> B
  fcStep<3, 0>(sB + L_A, Bx, H, lane);
  __syncthreads();
  gstage<21, 7, 0, 3>(sB + L_A, wsp, WS_W2, wid, lane);       // FC2 chunk a -> A
  fcStep<2, 3>(sB + L_B, Bx, H, lane);

  BU By[7];
#pragma unroll
  for (int ti = 0; ti < 7; ++ti) {
#pragma unroll
    for (int r = 0; r < 4; ++r) { float x = H[ti][r]; H[ti][r] = fmaxf(x, 0.2f * x); }
#pragma unroll
    for (int r = 0; r < 4; ++r) By[ti].u[r] = dup_cvt(H[ti][r]);
  }
  f32x4 G[7];
#pragma unroll
  for (int ti = 0; ti < 7; ++ti) G[ti] = ((const f32x4*)(sB + L_B2))[ti * 4 + grp];
  __syncthreads();

  // ================ FC2: g = leaky(W2 h + b2) ================
  gstage<14, 7, 3, 2>(sB + L_B, wsp, WS_W2, wid, lane);       // FC2 chunk b -> B
  fcStep<3, 0>(sB + L_A, By, G, lane);
  __syncthreads();
  gstage<14, 7, 5, 2>(sB + L_A, wsp, WS_W2, wid, lane);       // FC2 chunk c -> A
  fcStep<2, 3>(sB + L_B, By, G, lane);
  __syncthreads();
  fcStep<2, 5>(sB + L_A, By, G, lane);

  // ================ FC3: out = W3 . leaky(g) + b3 ================
  float pd = 0.f;
#pragma unroll
  for (int ti = 0; ti < 7; ++ti) {
    f32x4 w3v = ((const f32x4*)(sB + L_W3))[ti * 4 + grp];
#pragma unroll
    for (int r = 0; r < 4; ++r) {
      float g = G[ti][r];
      g = fmaxf(g, 0.2f * g);
      pd = fmaf(w3v[r], g, pd);
    }
  }
  pd += __shfl_xor(pd, 16);
  pd += __shfl_xor(pd, 32);
  if (lane < 16) out[blockIdx.x * NBB + wid * 16 + lane] = pd + c_b3;
}

extern "C" void kernel_launch(void* const* d_in, const int* in_sizes, int n_in,
                              void* d_out, int out_size, void* d_ws, size_t ws_size,
                              hipStream_t stream)
{
  const int*   dots    = (const int*)d_in[0];
  const float* w_each  = (const float*)d_in[1];
  const float* b_each  = (const float*)d_in[2];
  const float* w_not   = (const float*)d_in[3];
  const float* b_not   = (const float*)d_in[4];
  const float* w_not2  = (const float*)d_in[5];
  const float* b_not2  = (const float*)d_in[6];
  const float* w_empty = (const float*)d_in[7];
  const float* b_empty = (const float*)d_in[8];
  const float* W1 = (const float*)d_in[9];
  const float* b1 = (const float*)d_in[10];
  const float* W2 = (const float*)d_in[11];
  const float* b2 = (const float*)d_in[12];
  const float* W3 = (const float*)d_in[13];
  const float* b3 = (const float*)d_in[14];

  (void)in_sizes; (void)n_in; (void)out_size; (void)ws_size;

  ushort* wsp = (ushort*)d_ws;
  uint*   MKg = (uint*)((char*)d_ws + WS_MK_BYTE);

  k_prep<<<SETUP_BLOCKS + BN / 256, 256, 0, stream>>>(
      w_each, w_not, w_not2, w_empty, W1, W2, dots, wsp, MKg);
  k_main<<<NBLK, NT, 0, stream>>>(
      MKg, wsp, b_each, b_not, b_not2, b_empty, b1, b2, W3, b3, (float*)d_out);
}